// Round 3
// baseline (1112.470 us; speedup 1.0000x reference)
//
#include <hip/hip_runtime.h>
#include <hip/hip_bf16.h>
#include <math.h>

#define NNODES 65536
#define NEDGES 1048576
#define NGRAPHS 64

typedef __attribute__((ext_vector_type(8))) short short8;
typedef __attribute__((ext_vector_type(4))) float f32x4;

// ---- order-preserving float<->uint encoding for atomicMax-based max ----
__device__ __forceinline__ unsigned encf(float f) {
    unsigned u = __float_as_uint(f);
    return (u & 0x80000000u) ? ~u : (u | 0x80000000u);
}
__device__ __forceinline__ float decf(unsigned u) {
    unsigned v = (u & 0x80000000u) ? (u & 0x7FFFFFFFu) : ~u;
    return __uint_as_float(v);
}
#define ENC_NEG_INF 0x007FFFFFu   // encf(-inf)

// RNE float -> bf16 bits (finite values only)
__device__ __forceinline__ unsigned bfbits(float f) {
    unsigned u = __float_as_uint(f);
    return (u + 0x7FFFu + ((u >> 16) & 1u)) >> 16;
}
__device__ __forceinline__ unsigned pk2(float a, float b) {
    return bfbits(a) | (bfbits(b) << 16);
}
__device__ __forceinline__ float bflo(unsigned p) { return __uint_as_float(p << 16); }
__device__ __forceinline__ float bfhi(unsigned p) { return __uint_as_float(p & 0xFFFF0000u); }

// ============================ CSR build ============================
__global__ void k_init(int* deg, int* cursor, unsigned* poolEnc) {
    int i = blockIdx.x * 256 + threadIdx.x;
    if (i < NNODES) { deg[i] = 0; cursor[i] = 0; }
    if (i < NGRAPHS * 256) poolEnc[i] = ENC_NEG_INF;
}

__global__ void k_count(const int* __restrict__ ei, int* deg) {
    int e = blockIdx.x * 256 + threadIdx.x;
    atomicAdd(&deg[ei[NEDGES + e]], 1);
}

__global__ void k_scan1(const int* __restrict__ deg, int* rowptr, int* bsum) {
    __shared__ int s[256];
    int t = threadIdx.x, b = blockIdx.x;
    int v = deg[b * 256 + t];
    s[t] = v;
    __syncthreads();
    for (int off = 1; off < 256; off <<= 1) {
        int x = (t >= off) ? s[t - off] : 0;
        __syncthreads();
        if (t >= off) s[t] += x;
        __syncthreads();
    }
    rowptr[b * 256 + t] = s[t] - v;       // local exclusive
    if (t == 255) bsum[b] = s[255];
}

__global__ void k_scan2(const int* __restrict__ bsum, int* boff) {
    __shared__ int s[256];
    int t = threadIdx.x;
    int v = bsum[t];
    s[t] = v;
    __syncthreads();
    for (int off = 1; off < 256; off <<= 1) {
        int x = (t >= off) ? s[t - off] : 0;
        __syncthreads();
        if (t >= off) s[t] += x;
        __syncthreads();
    }
    boff[t] = s[t] - v;                   // exclusive block offsets
}

__global__ void k_scan3(int* rowptr, const int* __restrict__ boff) {
    int i = blockIdx.x * 256 + threadIdx.x;
    rowptr[i] += boff[blockIdx.x];
    if (i == 0) rowptr[NNODES] = NEDGES;
}

__global__ void k_scatter(const int* __restrict__ ei, const int* __restrict__ rowptr,
                          int* cursor, int* csr_src, int* csr_dst) {
    int e = blockIdx.x * 256 + threadIdx.x;
    int s = ei[e], d = ei[NEDGES + e];
    int pos = rowptr[d] + atomicAdd(&cursor[d], 1);
    csr_src[pos] = s;
    csr_dst[pos] = d;
}

// ============================ U/V precompute ============================
// U[i] = X[i] @ (W1_top - W1_bot) + b1  (fp32, dst-local, L1-cached in k_agg)
// V[i] = X[i] @ W1_bot                  (bf16: the random-gathered operand)
template <int FIN, int H>
__global__ __launch_bounds__(256) void k_uv(const float* __restrict__ X,
                                            const float* __restrict__ W1,
                                            const float* __restrict__ B1,
                                            float* __restrict__ U,
                                            unsigned short* __restrict__ Vb) {
    constexpr int NPT = (16 * H) / 256;   // nodes per thread
    __shared__ float xs[16][FIN];
    int tid = threadIdx.x;
    int n0 = blockIdx.x * 16;
    for (int idx = tid; idx < 16 * FIN; idx += 256)
        xs[idx / FIN][idx % FIN] = X[(size_t)(n0 + idx / FIN) * FIN + (idx % FIN)];
    __syncthreads();
    int h = tid & (H - 1);
    int nb = (tid / H) * NPT;
    float u[NPT], v[NPT];
    float bb = B1[h];
#pragma unroll
    for (int n = 0; n < NPT; n++) { u[n] = bb; v[n] = 0.f; }
    for (int f = 0; f < FIN; f++) {
        float wt = W1[f * H + h];
        float wb = W1[(FIN + f) * H + h];
        float wd = wt - wb;
#pragma unroll
        for (int n = 0; n < NPT; n++) {
            float xv = xs[nb + n][f];
            u[n] += xv * wd;
            v[n] += xv * wb;
        }
    }
#pragma unroll
    for (int n = 0; n < NPT; n++) {
        U[(size_t)(n0 + nb + n) * H + h] = u[n];
        Vb[(size_t)(n0 + nb + n) * H + h] = (unsigned short)bfbits(v[n]);
    }
}

// ================= fused edge-GEMM (MFMA bf16) + segment-max =================
// Block owns 16 dst nodes + all their in-edges (CSR) -> no global atomics.
// Register budget model (rounds 0-2 evidence): waves_per_eu min=4 caps the
// unified VGPR+AGPR file at 128/thread; the allocator parks the W2 fragments
// (Bf = CPW*H/128 regs) in AGPRs and the ARCH side spills when construction+
// acc+addressing exceed the remainder (measured 380+ MiB scratch writes).
// Fix: many narrow column-waves so Bf is small (CPW=16 -> NT=1) and the whole
// kernel fits under 128 regs with zero scratch. waves_per_eu(4,4) pins the
// allocator target at exactly 4 waves/SIMD.
template <int H, int F, int RWAVES, int CWAVES>
__global__ __launch_bounds__(RWAVES * CWAVES * 64)
__attribute__((amdgpu_waves_per_eu(4, 4)))
void k_agg(const float* __restrict__ U,
           const unsigned short* __restrict__ Vb,
           const float* __restrict__ W2,
           const float* __restrict__ B2,
           const int* __restrict__ rowptr,
           const int* __restrict__ csr_src,
           const int* __restrict__ csr_dst,
           float* __restrict__ Y) {
    constexpr int BLOCK = RWAVES * CWAVES * 64;
    constexpr int TR = 32 * RWAVES;         // edge rows per tile
    constexpr int HP = H + 8;               // padded row (bf16 units), 16B-aligned frags
    constexpr int CPW = F / CWAVES;         // cols per wave
    constexpr int NT = CPW / 16;            // n-tiles per wave
    constexpr int KS = H / 32;              // k-steps
    constexpr int ACCSTR = F + 1;           // bank-spread accumulator stride
    constexpr int LPR = H / 8;              // threads per hidden row (8 elems each)
    constexpr int RPP = BLOCK / LPR;        // rows per construction pass
    static_assert(H % 32 == 0 && NT >= 1 && RPP >= 1, "shape");

    __shared__ unsigned short hs[TR * HP];  // hidden tile, bf16
    __shared__ unsigned accs[16 * ACCSTR];  // per-slot running max (encoded)
    __shared__ int srcA[TR];
    __shared__ signed char slotB[TR];

    int tid = threadIdx.x;
    int n0 = blockIdx.x * 16;

    int ln = tid & 15;              // MFMA n/m lane index
    int qd = (tid >> 4) & 3;        // MFMA quad
    int wv = tid >> 6;
    int rw = wv / CWAVES;           // row group
    int cw = wv % CWAVES;           // col wave

    // ---- load W2 fragments into registers (bf16), once ----
    short8 Bf[NT][KS];
#pragma unroll
    for (int nt = 0; nt < NT; nt++) {
        int col = cw * CPW + nt * 16 + ln;
#pragma unroll
        for (int ks = 0; ks < KS; ks++) {
            int kb = ks * 32 + qd * 8;
            short8 b;
#pragma unroll
            for (int j = 0; j < 8; j++)
                b[j] = (short)bfbits(W2[(size_t)(kb + j) * F + col]);
            Bf[nt][ks] = b;
        }
    }

    for (int idx = tid; idx < 16 * ACCSTR; idx += BLOCK) accs[idx] = ENC_NEG_INF;

    int e0 = rowptr[n0], e1 = rowptr[n0 + 16];

    int rid = tid / LPR;            // construction: my first row
    int kk = (tid % LPR) * 8;       // construction: my 8-elem chunk

    for (int base = e0; base < e1; base += TR) {
        __syncthreads();            // prev tile fully consumed
        if (tid < TR) {
            int p = base + tid;
            if (p < e1) { srcA[tid] = csr_src[p]; slotB[tid] = (signed char)(csr_dst[p] - n0); }
            else        { srcA[tid] = 0;          slotB[tid] = -1; }
        }
        __syncthreads();

        // ---- build hidden tile: hs[r][k] = bf16(relu(U[dst,k] + V[src,k])) ----
#pragma unroll
        for (int r0 = 0; r0 < TR; r0 += RPP) {
            int r = r0 + rid;
            if (RPP > TR || r < TR) {
                int sl = slotB[r];
                uint4 w;
                if (sl >= 0) {
                    int src = srcA[r];
                    const float4 ua = *(const float4*)&U[(size_t)(n0 + sl) * H + kk];
                    const float4 ub = *(const float4*)&U[(size_t)(n0 + sl) * H + kk + 4];
                    const uint4 vv = *(const uint4*)&Vb[(size_t)src * H + kk];
                    w.x = pk2(fmaxf(ua.x + bflo(vv.x), 0.f), fmaxf(ua.y + bfhi(vv.x), 0.f));
                    w.y = pk2(fmaxf(ua.z + bflo(vv.y), 0.f), fmaxf(ua.w + bfhi(vv.y), 0.f));
                    w.z = pk2(fmaxf(ub.x + bflo(vv.z), 0.f), fmaxf(ub.y + bfhi(vv.z), 0.f));
                    w.w = pk2(fmaxf(ub.z + bflo(vv.w), 0.f), fmaxf(ub.w + bfhi(vv.w), 0.f));
                } else {
                    w = (uint4){0u, 0u, 0u, 0u};
                }
                *(uint4*)&hs[r * HP + kk] = w;
            }
        }
        __syncthreads();

        // ---- MFMA: [32 rows x CPW cols] per wave ----
        f32x4 acc[2][NT];
#pragma unroll
        for (int mt = 0; mt < 2; mt++)
#pragma unroll
            for (int nt = 0; nt < NT; nt++)
                acc[mt][nt] = (f32x4){0.f, 0.f, 0.f, 0.f};

#pragma unroll
        for (int ks = 0; ks < KS; ks++) {
            int ko = ks * 32 + qd * 8;
            short8 a0 = *(const short8*)&hs[(rw * 32 + ln) * HP + ko];
            short8 a1 = *(const short8*)&hs[(rw * 32 + 16 + ln) * HP + ko];
#pragma unroll
            for (int nt = 0; nt < NT; nt++) {
                acc[0][nt] = __builtin_amdgcn_mfma_f32_16x16x32_bf16(a0, Bf[nt][ks], acc[0][nt], 0, 0, 0);
                acc[1][nt] = __builtin_amdgcn_mfma_f32_16x16x32_bf16(a1, Bf[nt][ks], acc[1][nt], 0, 0, 0);
            }
        }

        // ---- segmented max: merge slot-runs in registers, then LDS atomicMax ----
#pragma unroll
        for (int mt = 0; mt < 2; mt++) {
            int rbase = rw * 32 + mt * 16 + qd * 4;
            char4 ss = *(const char4*)&slotB[rbase];
#pragma unroll
            for (int nt = 0; nt < NT; nt++) {
                int colw = cw * CPW + nt * 16 + ln;
                float c0 = acc[mt][nt][0], c1 = acc[mt][nt][1];
                float c2 = acc[mt][nt][2], c3 = acc[mt][nt][3];
                float m3 = c3;
                float m2 = (ss.z == ss.w) ? fmaxf(c2, m3) : c2;
                float m1 = (ss.y == ss.z) ? fmaxf(c1, m2) : c1;
                float m0 = (ss.x == ss.y) ? fmaxf(c0, m1) : c0;
                if (ss.x >= 0)                 atomicMax(&accs[(int)ss.x * ACCSTR + colw], encf(m0));
                if (ss.y >= 0 && ss.y != ss.x) atomicMax(&accs[(int)ss.y * ACCSTR + colw], encf(m1));
                if (ss.z >= 0 && ss.z != ss.y) atomicMax(&accs[(int)ss.z * ACCSTR + colw], encf(m2));
                if (ss.w >= 0 && ss.w != ss.z) atomicMax(&accs[(int)ss.w * ACCSTR + colw], encf(m3));
            }
        }
    }
    __syncthreads();

    for (int idx = tid; idx < 16 * F; idx += BLOCK) {
        int sl = idx / F, cc = idx % F;
        float m = decf(accs[sl * ACCSTR + cc]);
        float o = isfinite(m) ? (m + B2[cc]) : 0.f;   // empty segment -> 0
        Y[(size_t)(n0 + sl) * F + cc] = o;
    }
}

// ============================ global max-pool + FC ============================
__global__ void k_pool(const float* __restrict__ X3, const int* __restrict__ batch,
                       unsigned* poolEnc) {
    int gph = blockIdx.x;
    int seg = blockIdx.y;
    int c = threadIdx.x;
    int lo = 0, hi = NNODES;
    while (lo < hi) { int mid = (lo + hi) >> 1; if (batch[mid] < gph) lo = mid + 1; else hi = mid; }
    int start = lo;
    hi = NNODES;
    while (lo < hi) { int mid = (lo + hi) >> 1; if (batch[mid] < gph + 1) lo = mid + 1; else hi = mid; }
    int end = lo;
    int chunk = (end - start + 7) >> 3;
    int s = start + seg * chunk;
    int e = min(end, s + chunk);
    float m = -INFINITY;
    for (int n = s; n < e; n++) m = fmaxf(m, X3[(size_t)n * 256 + c]);
    atomicMax(&poolEnc[gph * 256 + c], encf(m));
}

__global__ __launch_bounds__(128) void k_fc(const unsigned* __restrict__ poolEnc,
                                            const float* __restrict__ Wfc,
                                            const float* __restrict__ Bfc,
                                            float* __restrict__ out) {
    __shared__ float p[256];
    int gph = blockIdx.x, c = threadIdx.x;
    for (int k = c; k < 256; k += 128) {
        float m = decf(poolEnc[gph * 256 + k]);
        p[k] = isfinite(m) ? m : 0.f;
    }
    __syncthreads();
    float s = Bfc[c];
    for (int k = 0; k < 256; k++) s += p[k] * Wfc[k * 128 + c];
    out[gph * 128 + c] = s;
}

// ============================ launch ============================
extern "C" void kernel_launch(void* const* d_in, const int* in_sizes, int n_in,
                              void* d_out, int out_size, void* d_ws, size_t ws_size,
                              hipStream_t stream) {
    const float* x     = (const float*)d_in[0];
    const int*   ei    = (const int*)d_in[1];
    const int*   batch = (const int*)d_in[2];
    const float* w1_1 = (const float*)d_in[3];
    const float* b1_1 = (const float*)d_in[4];
    const float* w2_1 = (const float*)d_in[5];
    const float* b2_1 = (const float*)d_in[6];
    const float* w1_2 = (const float*)d_in[7];
    const float* b1_2 = (const float*)d_in[8];
    const float* w2_2 = (const float*)d_in[9];
    const float* b2_2 = (const float*)d_in[10];
    const float* w1_3 = (const float*)d_in[11];
    const float* b1_3 = (const float*)d_in[12];
    const float* w2_3 = (const float*)d_in[13];
    const float* b2_3 = (const float*)d_in[14];
    const float* wfc  = (const float*)d_in[15];
    const float* bfc  = (const float*)d_in[16];
    float* out = (float*)d_out;

    char* ws = (char*)d_ws;
    size_t off = 0;
    auto alloc = [&](size_t bytes) {
        void* p = ws + off;
        off = (off + bytes + 255) & ~(size_t)255;
        return p;
    };
    int* deg      = (int*)alloc((size_t)NNODES * 4);
    int* cursor   = (int*)alloc((size_t)NNODES * 4);
    int* rowptr   = (int*)alloc((size_t)(NNODES + 1) * 4);
    int* bsum     = (int*)alloc(256 * 4);
    int* boff     = (int*)alloc(256 * 4);
    int* csr_src  = (int*)alloc((size_t)NEDGES * 4);
    int* csr_dst  = (int*)alloc((size_t)NEDGES * 4);
    float* U      = (float*)alloc((size_t)NNODES * 256 * 4);
    unsigned short* V = (unsigned short*)alloc((size_t)NNODES * 256 * 2);
    float* x1     = (float*)alloc((size_t)NNODES * 64 * 4);
    float* x2     = (float*)alloc((size_t)NNODES * 128 * 4);
    float* x3     = (float*)alloc((size_t)NNODES * 256 * 4);
    unsigned* poolEnc = (unsigned*)alloc((size_t)NGRAPHS * 256 * 4);
    (void)ws_size; (void)in_sizes; (void)n_in; (void)out_size;

    // CSR by dst (shared across the 3 layers)
    k_init<<<256, 256, 0, stream>>>(deg, cursor, poolEnc);
    k_count<<<NEDGES / 256, 256, 0, stream>>>(ei, deg);
    k_scan1<<<256, 256, 0, stream>>>(deg, rowptr, bsum);
    k_scan2<<<1, 256, 0, stream>>>(bsum, boff);
    k_scan3<<<256, 256, 0, stream>>>(rowptr, boff);
    k_scatter<<<NEDGES / 256, 256, 0, stream>>>(ei, rowptr, cursor, csr_src, csr_dst);

    // layer 1: F_in=3, H=64, F=64   (2x2 waves, TR=64, Bf=16 regs)
    k_uv<3, 64><<<NNODES / 16, 256, 0, stream>>>(x, w1_1, b1_1, U, V);
    k_agg<64, 64, 2, 2><<<NNODES / 16, 256, 0, stream>>>(U, V, w2_1, b2_1, rowptr, csr_src, csr_dst, x1);
    // layer 2: F_in=64, H=128, F=128  (1x8 waves, 512 thr, CPW=16, Bf=16 regs)
    k_uv<64, 128><<<NNODES / 16, 256, 0, stream>>>(x1, w1_2, b1_2, U, V);
    k_agg<128, 128, 1, 8><<<NNODES / 16, 512, 0, stream>>>(U, V, w2_2, b2_2, rowptr, csr_src, csr_dst, x2);
    // layer 3: F_in=128, H=256, F=256  (1x16 waves, 1024 thr, CPW=16, Bf=32 regs)
    k_uv<128, 256><<<NNODES / 16, 256, 0, stream>>>(x2, w1_3, b1_3, U, V);
    k_agg<256, 256, 1, 16><<<NNODES / 16, 1024, 0, stream>>>(U, V, w2_3, b2_3, rowptr, csr_src, csr_dst, x3);

    // global max pool + FC
    k_pool<<<dim3(NGRAPHS, 8), 256, 0, stream>>>(x3, batch, poolEnc);
    k_fc<<<NGRAPHS, 128, 0, stream>>>(poolEnc, wfc, bfc, out);
}

// Round 4
// 1039.314 us; speedup vs baseline: 1.0704x; 1.0704x over previous
//
#include <hip/hip_runtime.h>
#include <hip/hip_bf16.h>
#include <math.h>

#define NNODES 65536
#define NEDGES 1048576
#define NGRAPHS 64

typedef __attribute__((ext_vector_type(8))) short short8;
typedef __attribute__((ext_vector_type(4))) float f32x4;

// ---- order-preserving float<->uint encoding for atomicMax-based max ----
__device__ __forceinline__ unsigned encf(float f) {
    unsigned u = __float_as_uint(f);
    return (u & 0x80000000u) ? ~u : (u | 0x80000000u);
}
__device__ __forceinline__ float decf(unsigned u) {
    unsigned v = (u & 0x80000000u) ? (u & 0x7FFFFFFFu) : ~u;
    return __uint_as_float(v);
}
#define ENC_NEG_INF 0x007FFFFFu   // encf(-inf)

// RNE float -> bf16 bits (finite values only)
__device__ __forceinline__ unsigned bfbits(float f) {
    unsigned u = __float_as_uint(f);
    return (u + 0x7FFFu + ((u >> 16) & 1u)) >> 16;
}
__device__ __forceinline__ unsigned pk2(float a, float b) {
    return bfbits(a) | (bfbits(b) << 16);
}
__device__ __forceinline__ float bflo(unsigned p) { return __uint_as_float(p << 16); }
__device__ __forceinline__ float bfhi(unsigned p) { return __uint_as_float(p & 0xFFFF0000u); }

// ============================ CSR build ============================
__global__ void k_init(int* deg, int* cursor, unsigned* poolEnc) {
    int i = blockIdx.x * 256 + threadIdx.x;
    if (i < NNODES) { deg[i] = 0; cursor[i] = 0; }
    if (i < NGRAPHS * 256) poolEnc[i] = ENC_NEG_INF;
}

__global__ void k_count(const int* __restrict__ ei, int* deg) {
    int e = blockIdx.x * 256 + threadIdx.x;
    atomicAdd(&deg[ei[NEDGES + e]], 1);
}

__global__ void k_scan1(const int* __restrict__ deg, int* rowptr, int* bsum) {
    __shared__ int s[256];
    int t = threadIdx.x, b = blockIdx.x;
    int v = deg[b * 256 + t];
    s[t] = v;
    __syncthreads();
    for (int off = 1; off < 256; off <<= 1) {
        int x = (t >= off) ? s[t - off] : 0;
        __syncthreads();
        if (t >= off) s[t] += x;
        __syncthreads();
    }
    rowptr[b * 256 + t] = s[t] - v;       // local exclusive
    if (t == 255) bsum[b] = s[255];
}

__global__ void k_scan2(const int* __restrict__ bsum, int* boff) {
    __shared__ int s[256];
    int t = threadIdx.x;
    int v = bsum[t];
    s[t] = v;
    __syncthreads();
    for (int off = 1; off < 256; off <<= 1) {
        int x = (t >= off) ? s[t - off] : 0;
        __syncthreads();
        if (t >= off) s[t] += x;
        __syncthreads();
    }
    boff[t] = s[t] - v;                   // exclusive block offsets
}

__global__ void k_scan3(int* rowptr, const int* __restrict__ boff) {
    int i = blockIdx.x * 256 + threadIdx.x;
    rowptr[i] += boff[blockIdx.x];
    if (i == 0) rowptr[NNODES] = NEDGES;
}

__global__ void k_scatter(const int* __restrict__ ei, const int* __restrict__ rowptr,
                          int* cursor, int* csr_src, int* csr_dst) {
    int e = blockIdx.x * 256 + threadIdx.x;
    int s = ei[e], d = ei[NEDGES + e];
    int pos = rowptr[d] + atomicAdd(&cursor[d], 1);
    csr_src[pos] = s;
    csr_dst[pos] = d;
}

// ============================ U/V precompute ============================
// U[i] = X[i] @ (W1_top - W1_bot) + b1  (fp32, dst-local, L1-cached in k_agg)
// V[i] = X[i] @ W1_bot                  (bf16: the random-gathered operand)
template <int FIN, int H>
__global__ __launch_bounds__(256) void k_uv(const float* __restrict__ X,
                                            const float* __restrict__ W1,
                                            const float* __restrict__ B1,
                                            float* __restrict__ U,
                                            unsigned short* __restrict__ Vb) {
    constexpr int NPT = (16 * H) / 256;   // nodes per thread
    __shared__ float xs[16][FIN];
    int tid = threadIdx.x;
    int n0 = blockIdx.x * 16;
    for (int idx = tid; idx < 16 * FIN; idx += 256)
        xs[idx / FIN][idx % FIN] = X[(size_t)(n0 + idx / FIN) * FIN + (idx % FIN)];
    __syncthreads();
    int h = tid & (H - 1);
    int nb = (tid / H) * NPT;
    float u[NPT], v[NPT];
    float bb = B1[h];
#pragma unroll
    for (int n = 0; n < NPT; n++) { u[n] = bb; v[n] = 0.f; }
    for (int f = 0; f < FIN; f++) {
        float wt = W1[f * H + h];
        float wb = W1[(FIN + f) * H + h];
        float wd = wt - wb;
#pragma unroll
        for (int n = 0; n < NPT; n++) {
            float xv = xs[nb + n][f];
            u[n] += xv * wd;
            v[n] += xv * wb;
        }
    }
#pragma unroll
    for (int n = 0; n < NPT; n++) {
        U[(size_t)(n0 + nb + n) * H + h] = u[n];
        Vb[(size_t)(n0 + nb + n) * H + h] = (unsigned short)bfbits(v[n]);
    }
}

// ================= fused edge-GEMM (MFMA bf16) + segment-max =================
// Block owns 16 dst nodes + all their in-edges (CSR) -> no global atomics.
// Shape chosen so register demand < 64 (round-3 evidence: CPW=16 -> NT=1 ->
// Bf=KS short8 -> VGPR_Count=52, zero scratch). No occupancy attribute:
// at <=64 VGPR and <=2x LDS, TWO blocks co-reside per CU, so one block's
// construction/gather phase overlaps the other block's MFMA phase (the
// phase-serialization stall was ~80% of round-3's cycles: 9100 cyc/tile vs
// ~1000 cyc of work, occupancy capped at 44% by waves_per_eu(4,4)).
template <int H, int F, int RWAVES, int CWAVES>
__global__ __launch_bounds__(RWAVES * CWAVES * 64)
void k_agg(const float* __restrict__ U,
           const unsigned short* __restrict__ Vb,
           const float* __restrict__ W2,
           const float* __restrict__ B2,
           const int* __restrict__ rowptr,
           const int* __restrict__ csr_src,
           const int* __restrict__ csr_dst,
           float* __restrict__ Y) {
    constexpr int BLOCK = RWAVES * CWAVES * 64;
    constexpr int TR = 32 * RWAVES;         // edge rows per tile
    constexpr int HP = H + 8;               // padded row (bf16 units), 16B-aligned frags
    constexpr int CPW = F / CWAVES;         // cols per wave
    constexpr int NT = CPW / 16;            // n-tiles per wave
    constexpr int KS = H / 32;              // k-steps
    constexpr int ACCSTR = F + 1;           // bank-spread accumulator stride
    constexpr int LPR = H / 8;              // threads per hidden row (8 elems each)
    constexpr int RPP = BLOCK / LPR;        // rows per construction pass
    static_assert(H % 32 == 0 && NT >= 1 && RPP >= 1, "shape");

    __shared__ unsigned short hs[TR * HP];  // hidden tile, bf16
    __shared__ unsigned accs[16 * ACCSTR];  // per-slot running max (encoded)
    __shared__ int srcA[TR];
    __shared__ signed char slotB[TR];

    int tid = threadIdx.x;
    int n0 = blockIdx.x * 16;

    int ln = tid & 15;              // MFMA n/m lane index
    int qd = (tid >> 4) & 3;        // MFMA quad
    int wv = tid >> 6;
    int rw = wv / CWAVES;           // row group
    int cw = wv % CWAVES;           // col wave

    // ---- load W2 fragments into registers (bf16), once ----
    short8 Bf[NT][KS];
#pragma unroll
    for (int nt = 0; nt < NT; nt++) {
        int col = cw * CPW + nt * 16 + ln;
#pragma unroll
        for (int ks = 0; ks < KS; ks++) {
            int kb = ks * 32 + qd * 8;
            short8 b;
#pragma unroll
            for (int j = 0; j < 8; j++)
                b[j] = (short)bfbits(W2[(size_t)(kb + j) * F + col]);
            Bf[nt][ks] = b;
        }
    }

    for (int idx = tid; idx < 16 * ACCSTR; idx += BLOCK) accs[idx] = ENC_NEG_INF;

    int e0 = rowptr[n0], e1 = rowptr[n0 + 16];

    int rid = tid / LPR;            // construction: my first row
    int kk = (tid % LPR) * 8;       // construction: my 8-elem chunk

    for (int base = e0; base < e1; base += TR) {
        __syncthreads();            // prev tile fully consumed
        if (tid < TR) {
            int p = base + tid;
            if (p < e1) { srcA[tid] = csr_src[p]; slotB[tid] = (signed char)(csr_dst[p] - n0); }
            else        { srcA[tid] = 0;          slotB[tid] = -1; }
        }
        __syncthreads();

        // ---- build hidden tile: hs[r][k] = bf16(relu(U[dst,k] + V[src,k])) ----
#pragma unroll
        for (int r0 = 0; r0 < TR; r0 += RPP) {
            int r = r0 + rid;
            if (RPP > TR || r < TR) {
                int sl = slotB[r];
                uint4 w;
                if (sl >= 0) {
                    int src = srcA[r];
                    const float4 ua = *(const float4*)&U[(size_t)(n0 + sl) * H + kk];
                    const float4 ub = *(const float4*)&U[(size_t)(n0 + sl) * H + kk + 4];
                    const uint4 vv = *(const uint4*)&Vb[(size_t)src * H + kk];
                    w.x = pk2(fmaxf(ua.x + bflo(vv.x), 0.f), fmaxf(ua.y + bfhi(vv.x), 0.f));
                    w.y = pk2(fmaxf(ua.z + bflo(vv.y), 0.f), fmaxf(ua.w + bfhi(vv.y), 0.f));
                    w.z = pk2(fmaxf(ub.x + bflo(vv.z), 0.f), fmaxf(ub.y + bfhi(vv.z), 0.f));
                    w.w = pk2(fmaxf(ub.z + bflo(vv.w), 0.f), fmaxf(ub.w + bfhi(vv.w), 0.f));
                } else {
                    w = (uint4){0u, 0u, 0u, 0u};
                }
                *(uint4*)&hs[r * HP + kk] = w;
            }
        }
        __syncthreads();

        // ---- MFMA: [32 rows x CPW cols] per wave ----
        f32x4 acc[2][NT];
#pragma unroll
        for (int mt = 0; mt < 2; mt++)
#pragma unroll
            for (int nt = 0; nt < NT; nt++)
                acc[mt][nt] = (f32x4){0.f, 0.f, 0.f, 0.f};

#pragma unroll
        for (int ks = 0; ks < KS; ks++) {
            int ko = ks * 32 + qd * 8;
            short8 a0 = *(const short8*)&hs[(rw * 32 + ln) * HP + ko];
            short8 a1 = *(const short8*)&hs[(rw * 32 + 16 + ln) * HP + ko];
#pragma unroll
            for (int nt = 0; nt < NT; nt++) {
                acc[0][nt] = __builtin_amdgcn_mfma_f32_16x16x32_bf16(a0, Bf[nt][ks], acc[0][nt], 0, 0, 0);
                acc[1][nt] = __builtin_amdgcn_mfma_f32_16x16x32_bf16(a1, Bf[nt][ks], acc[1][nt], 0, 0, 0);
            }
        }

        // ---- segmented max: merge slot-runs in registers, then LDS atomicMax ----
#pragma unroll
        for (int mt = 0; mt < 2; mt++) {
            int rbase = rw * 32 + mt * 16 + qd * 4;
            char4 ss = *(const char4*)&slotB[rbase];
#pragma unroll
            for (int nt = 0; nt < NT; nt++) {
                int colw = cw * CPW + nt * 16 + ln;
                float c0 = acc[mt][nt][0], c1 = acc[mt][nt][1];
                float c2 = acc[mt][nt][2], c3 = acc[mt][nt][3];
                float m3 = c3;
                float m2 = (ss.z == ss.w) ? fmaxf(c2, m3) : c2;
                float m1 = (ss.y == ss.z) ? fmaxf(c1, m2) : c1;
                float m0 = (ss.x == ss.y) ? fmaxf(c0, m1) : c0;
                if (ss.x >= 0)                 atomicMax(&accs[(int)ss.x * ACCSTR + colw], encf(m0));
                if (ss.y >= 0 && ss.y != ss.x) atomicMax(&accs[(int)ss.y * ACCSTR + colw], encf(m1));
                if (ss.z >= 0 && ss.z != ss.y) atomicMax(&accs[(int)ss.z * ACCSTR + colw], encf(m2));
                if (ss.w >= 0 && ss.w != ss.z) atomicMax(&accs[(int)ss.w * ACCSTR + colw], encf(m3));
            }
        }
    }
    __syncthreads();

    for (int idx = tid; idx < 16 * F; idx += BLOCK) {
        int sl = idx / F, cc = idx % F;
        float m = decf(accs[sl * ACCSTR + cc]);
        float o = isfinite(m) ? (m + B2[cc]) : 0.f;   // empty segment -> 0
        Y[(size_t)(n0 + sl) * F + cc] = o;
    }
}

// ============================ global max-pool + FC ============================
__global__ void k_pool(const float* __restrict__ X3, const int* __restrict__ batch,
                       unsigned* poolEnc) {
    int gph = blockIdx.x;
    int seg = blockIdx.y;
    int c = threadIdx.x;
    int lo = 0, hi = NNODES;
    while (lo < hi) { int mid = (lo + hi) >> 1; if (batch[mid] < gph) lo = mid + 1; else hi = mid; }
    int start = lo;
    hi = NNODES;
    while (lo < hi) { int mid = (lo + hi) >> 1; if (batch[mid] < gph + 1) lo = mid + 1; else hi = mid; }
    int end = lo;
    int chunk = (end - start + 7) >> 3;
    int s = start + seg * chunk;
    int e = min(end, s + chunk);
    float m = -INFINITY;
    for (int n = s; n < e; n++) m = fmaxf(m, X3[(size_t)n * 256 + c]);
    atomicMax(&poolEnc[gph * 256 + c], encf(m));
}

__global__ __launch_bounds__(128) void k_fc(const unsigned* __restrict__ poolEnc,
                                            const float* __restrict__ Wfc,
                                            const float* __restrict__ Bfc,
                                            float* __restrict__ out) {
    __shared__ float p[256];
    int gph = blockIdx.x, c = threadIdx.x;
    for (int k = c; k < 256; k += 128) {
        float m = decf(poolEnc[gph * 256 + k]);
        p[k] = isfinite(m) ? m : 0.f;
    }
    __syncthreads();
    float s = Bfc[c];
    for (int k = 0; k < 256; k++) s += p[k] * Wfc[k * 128 + c];
    out[gph * 128 + c] = s;
}

// ============================ launch ============================
extern "C" void kernel_launch(void* const* d_in, const int* in_sizes, int n_in,
                              void* d_out, int out_size, void* d_ws, size_t ws_size,
                              hipStream_t stream) {
    const float* x     = (const float*)d_in[0];
    const int*   ei    = (const int*)d_in[1];
    const int*   batch = (const int*)d_in[2];
    const float* w1_1 = (const float*)d_in[3];
    const float* b1_1 = (const float*)d_in[4];
    const float* w2_1 = (const float*)d_in[5];
    const float* b2_1 = (const float*)d_in[6];
    const float* w1_2 = (const float*)d_in[7];
    const float* b1_2 = (const float*)d_in[8];
    const float* w2_2 = (const float*)d_in[9];
    const float* b2_2 = (const float*)d_in[10];
    const float* w1_3 = (const float*)d_in[11];
    const float* b1_3 = (const float*)d_in[12];
    const float* w2_3 = (const float*)d_in[13];
    const float* b2_3 = (const float*)d_in[14];
    const float* wfc  = (const float*)d_in[15];
    const float* bfc  = (const float*)d_in[16];
    float* out = (float*)d_out;

    char* ws = (char*)d_ws;
    size_t off = 0;
    auto alloc = [&](size_t bytes) {
        void* p = ws + off;
        off = (off + bytes + 255) & ~(size_t)255;
        return p;
    };
    int* deg      = (int*)alloc((size_t)NNODES * 4);
    int* cursor   = (int*)alloc((size_t)NNODES * 4);
    int* rowptr   = (int*)alloc((size_t)(NNODES + 1) * 4);
    int* bsum     = (int*)alloc(256 * 4);
    int* boff     = (int*)alloc(256 * 4);
    int* csr_src  = (int*)alloc((size_t)NEDGES * 4);
    int* csr_dst  = (int*)alloc((size_t)NEDGES * 4);
    float* U      = (float*)alloc((size_t)NNODES * 256 * 4);
    unsigned short* V = (unsigned short*)alloc((size_t)NNODES * 256 * 2);
    float* x1     = (float*)alloc((size_t)NNODES * 64 * 4);
    float* x2     = (float*)alloc((size_t)NNODES * 128 * 4);
    float* x3     = (float*)alloc((size_t)NNODES * 256 * 4);
    unsigned* poolEnc = (unsigned*)alloc((size_t)NGRAPHS * 256 * 4);
    (void)ws_size; (void)in_sizes; (void)n_in; (void)out_size;

    // CSR by dst (shared across the 3 layers)
    k_init<<<256, 256, 0, stream>>>(deg, cursor, poolEnc);
    k_count<<<NEDGES / 256, 256, 0, stream>>>(ei, deg);
    k_scan1<<<256, 256, 0, stream>>>(deg, rowptr, bsum);
    k_scan2<<<1, 256, 0, stream>>>(bsum, boff);
    k_scan3<<<256, 256, 0, stream>>>(rowptr, boff);
    k_scatter<<<NEDGES / 256, 256, 0, stream>>>(ei, rowptr, cursor, csr_src, csr_dst);

    // layer 1: F_in=3, H=64, F=64   (2x2 waves, TR=64, Bf=16 regs)
    k_uv<3, 64><<<NNODES / 16, 256, 0, stream>>>(x, w1_1, b1_1, U, V);
    k_agg<64, 64, 2, 2><<<NNODES / 16, 256, 0, stream>>>(U, V, w2_1, b2_1, rowptr, csr_src, csr_dst, x1);
    // layer 2: F_in=64, H=128, F=128  (1x8 waves, 512 thr, CPW=16, Bf=16 regs)
    k_uv<64, 128><<<NNODES / 16, 256, 0, stream>>>(x1, w1_2, b1_2, U, V);
    k_agg<128, 128, 1, 8><<<NNODES / 16, 512, 0, stream>>>(U, V, w2_2, b2_2, rowptr, csr_src, csr_dst, x2);
    // layer 3: F_in=128, H=256, F=256  (1x16 waves, 1024 thr, CPW=16, Bf=32 regs)
    k_uv<128, 256><<<NNODES / 16, 256, 0, stream>>>(x2, w1_3, b1_3, U, V);
    k_agg<256, 256, 1, 16><<<NNODES / 16, 1024, 0, stream>>>(U, V, w2_3, b2_3, rowptr, csr_src, csr_dst, x3);

    // global max pool + FC
    k_pool<<<dim3(NGRAPHS, 8), 256, 0, stream>>>(x3, batch, poolEnc);
    k_fc<<<NGRAPHS, 128, 0, stream>>>(poolEnc, wfc, bfc, out);
}

// Round 5
// 930.847 us; speedup vs baseline: 1.1951x; 1.1165x over previous
//
#include <hip/hip_runtime.h>
#include <hip/hip_bf16.h>
#include <math.h>

#define NNODES 65536
#define NEDGES 1048576
#define NGRAPHS 64

typedef __attribute__((ext_vector_type(8))) short short8;
typedef __attribute__((ext_vector_type(4))) float f32x4;

// ---- order-preserving float<->uint encoding for atomicMax-based max ----
__device__ __forceinline__ unsigned encf(float f) {
    unsigned u = __float_as_uint(f);
    return (u & 0x80000000u) ? ~u : (u | 0x80000000u);
}
__device__ __forceinline__ float decf(unsigned u) {
    unsigned v = (u & 0x80000000u) ? (u & 0x7FFFFFFFu) : ~u;
    return __uint_as_float(v);
}
#define ENC_NEG_INF 0x007FFFFFu   // encf(-inf)

// RNE float -> bf16 bits (finite values only)
__device__ __forceinline__ unsigned bfbits(float f) {
    unsigned u = __float_as_uint(f);
    return (u + 0x7FFFu + ((u >> 16) & 1u)) >> 16;
}
__device__ __forceinline__ unsigned pk2(float a, float b) {
    return bfbits(a) | (bfbits(b) << 16);
}
__device__ __forceinline__ float bflo(unsigned p) { return __uint_as_float(p << 16); }
__device__ __forceinline__ float bfhi(unsigned p) { return __uint_as_float(p & 0xFFFF0000u); }

// ============================ CSR build ============================
__global__ void k_init(int* deg, int* cursor, unsigned* poolEnc) {
    int i = blockIdx.x * 256 + threadIdx.x;
    if (i < NNODES) { deg[i] = 0; cursor[i] = 0; }
    if (i < NGRAPHS * 256) poolEnc[i] = ENC_NEG_INF;
}

__global__ void k_count(const int* __restrict__ ei, int* deg) {
    int e = blockIdx.x * 256 + threadIdx.x;
    atomicAdd(&deg[ei[NEDGES + e]], 1);
}

__global__ void k_scan1(const int* __restrict__ deg, int* rowptr, int* bsum) {
    __shared__ int s[256];
    int t = threadIdx.x, b = blockIdx.x;
    int v = deg[b * 256 + t];
    s[t] = v;
    __syncthreads();
    for (int off = 1; off < 256; off <<= 1) {
        int x = (t >= off) ? s[t - off] : 0;
        __syncthreads();
        if (t >= off) s[t] += x;
        __syncthreads();
    }
    rowptr[b * 256 + t] = s[t] - v;       // local exclusive
    if (t == 255) bsum[b] = s[255];
}

__global__ void k_scan2(const int* __restrict__ bsum, int* boff) {
    __shared__ int s[256];
    int t = threadIdx.x;
    int v = bsum[t];
    s[t] = v;
    __syncthreads();
    for (int off = 1; off < 256; off <<= 1) {
        int x = (t >= off) ? s[t - off] : 0;
        __syncthreads();
        if (t >= off) s[t] += x;
        __syncthreads();
    }
    boff[t] = s[t] - v;                   // exclusive block offsets
}

__global__ void k_scan3(int* rowptr, const int* __restrict__ boff) {
    int i = blockIdx.x * 256 + threadIdx.x;
    rowptr[i] += boff[blockIdx.x];
    if (i == 0) rowptr[NNODES] = NEDGES;
}

__global__ void k_scatter(const int* __restrict__ ei, const int* __restrict__ rowptr,
                          int* cursor, int* csr_src, int* csr_dst) {
    int e = blockIdx.x * 256 + threadIdx.x;
    int s = ei[e], d = ei[NEDGES + e];
    int pos = rowptr[d] + atomicAdd(&cursor[d], 1);
    csr_src[pos] = s;
    csr_dst[pos] = d;
}

// ============================ U/V precompute ============================
// U[i] = X[i] @ (W1_top - W1_bot) + b1  (fp32, dst-local, L1-cached in k_agg)
// V[i] = X[i] @ W1_bot                  (bf16: the random-gathered operand)
template <int FIN, int H>
__global__ __launch_bounds__(256) void k_uv(const float* __restrict__ X,
                                            const float* __restrict__ W1,
                                            const float* __restrict__ B1,
                                            float* __restrict__ U,
                                            unsigned short* __restrict__ Vb) {
    constexpr int NPT = (16 * H) / 256;   // nodes per thread
    __shared__ float xs[16][FIN];
    int tid = threadIdx.x;
    int n0 = blockIdx.x * 16;
    for (int idx = tid; idx < 16 * FIN; idx += 256)
        xs[idx / FIN][idx % FIN] = X[(size_t)(n0 + idx / FIN) * FIN + (idx % FIN)];
    __syncthreads();
    int h = tid & (H - 1);
    int nb = (tid / H) * NPT;
    float u[NPT], v[NPT];
    float bb = B1[h];
#pragma unroll
    for (int n = 0; n < NPT; n++) { u[n] = bb; v[n] = 0.f; }
    for (int f = 0; f < FIN; f++) {
        float wt = W1[f * H + h];
        float wb = W1[(FIN + f) * H + h];
        float wd = wt - wb;
#pragma unroll
        for (int n = 0; n < NPT; n++) {
            float xv = xs[nb + n][f];
            u[n] += xv * wd;
            v[n] += xv * wb;
        }
    }
#pragma unroll
    for (int n = 0; n < NPT; n++) {
        U[(size_t)(n0 + nb + n) * H + h] = u[n];
        Vb[(size_t)(n0 + nb + n) * H + h] = (unsigned short)bfbits(v[n]);
    }
}

// ================= fused edge-GEMM (MFMA bf16) + segment-max =================
// Block owns 16 dst nodes + all their in-edges (CSR) -> no global atomics.
// Register-lean shapes (CPW=16 -> NT=1; round-3/4 evidence: no scratch) +
// round-1 software pipeline (now affordable at NT=1): double-buffered hidden
// tile, ONE barrier per tile, V-gathers + next-tile CSR issued BEFORE the
// previous tile's MFMA so the ~600cy random-gather latency and construction
// VALU hide under the MFMA + LDS-read phase of the prior tile. Rounds 0-4
// showed the 3-barrier lockstep loop serialized these (9.1K cyc/tile vs
// ~5K of actual pipe work).
template <int H, int F, int RWAVES, int CWAVES>
__global__ __launch_bounds__(RWAVES * CWAVES * 64)
void k_agg(const float* __restrict__ U,
           const unsigned short* __restrict__ Vb,
           const float* __restrict__ W2,
           const float* __restrict__ B2,
           const int* __restrict__ rowptr,
           const int* __restrict__ csr_src,
           const int* __restrict__ csr_dst,
           float* __restrict__ Y) {
    constexpr int BLOCK = RWAVES * CWAVES * 64;
    constexpr int TR = 32 * RWAVES;         // edge rows per tile
    constexpr int HP = H + 8;               // padded row (bf16 units), 16B-aligned frags
    constexpr int CPW = F / CWAVES;         // cols per wave
    constexpr int NT = CPW / 16;            // n-tiles per wave
    constexpr int KS = H / 32;              // k-steps
    constexpr int ACCSTR = F + 1;           // bank-spread accumulator stride
    constexpr int LPR = H / 8;              // threads per hidden row (8 elems each)
    constexpr int RPP = BLOCK / LPR;        // rows per construction pass
    constexpr int NPASS = TR / RPP;         // construction passes per tile
    static_assert(H % 32 == 0 && NT >= 1 && RPP >= 1 && TR % RPP == 0, "shape");

    __shared__ unsigned short hs[2][TR * HP];   // double-buffered hidden tile
    __shared__ unsigned accs[16 * ACCSTR];      // per-slot running max (encoded)
    __shared__ int srcA[2][TR];
    __shared__ __align__(4) signed char slotB[2][TR];

    int tid = threadIdx.x;
    int n0 = blockIdx.x * 16;

    int ln = tid & 15;              // MFMA n/m lane index
    int qd = (tid >> 4) & 3;        // MFMA quad
    int wv = tid >> 6;
    int rw = wv / CWAVES;           // row group
    int cw = wv % CWAVES;           // col wave

    // ---- load W2 fragments into registers (bf16), once ----
    short8 Bf[NT][KS];
#pragma unroll
    for (int nt = 0; nt < NT; nt++) {
        int col = cw * CPW + nt * 16 + ln;
#pragma unroll
        for (int ks = 0; ks < KS; ks++) {
            int kb = ks * 32 + qd * 8;
            short8 b;
#pragma unroll
            for (int j = 0; j < 8; j++)
                b[j] = (short)bfbits(W2[(size_t)(kb + j) * F + col]);
            Bf[nt][ks] = b;
        }
    }

    for (int idx = tid; idx < 16 * ACCSTR; idx += BLOCK) accs[idx] = ENC_NEG_INF;

    int e0 = rowptr[n0], e1 = rowptr[n0 + 16];
    int ntile = (e1 - e0 + TR - 1) / TR;

    int rid = tid / LPR;            // construction: my row within a pass
    int kk = (tid % LPR) * 8;       // construction: my 8-elem chunk

    // stage CSR metadata for tile 0
    if (tid < TR) {
        int p = e0 + tid;
        int s = 0; signed char sl = -1;
        if (p < e1) { s = csr_src[p]; sl = (signed char)(csr_dst[p] - n0); }
        srcA[0][tid] = s; slotB[0][tid] = sl;
    }
    __syncthreads();

    // MFMA + segmented-max for one completed tile (reads hs[buf])
    auto mfma_tile = [&](int buf, char4 s0, char4 s1) {
        f32x4 acc[2][NT];
#pragma unroll
        for (int mt = 0; mt < 2; mt++)
#pragma unroll
            for (int nt = 0; nt < NT; nt++)
                acc[mt][nt] = (f32x4){0.f, 0.f, 0.f, 0.f};

#pragma unroll
        for (int ks = 0; ks < KS; ks++) {
            int ko = ks * 32 + qd * 8;
            short8 a0 = *(const short8*)&hs[buf][(rw * 32 + ln) * HP + ko];
            short8 a1 = *(const short8*)&hs[buf][(rw * 32 + 16 + ln) * HP + ko];
#pragma unroll
            for (int nt = 0; nt < NT; nt++) {
                acc[0][nt] = __builtin_amdgcn_mfma_f32_16x16x32_bf16(a0, Bf[nt][ks], acc[0][nt], 0, 0, 0);
                acc[1][nt] = __builtin_amdgcn_mfma_f32_16x16x32_bf16(a1, Bf[nt][ks], acc[1][nt], 0, 0, 0);
            }
        }

#pragma unroll
        for (int mt = 0; mt < 2; mt++) {
            char4 ss = mt ? s1 : s0;
#pragma unroll
            for (int nt = 0; nt < NT; nt++) {
                int colw = cw * CPW + nt * 16 + ln;
                float c0 = acc[mt][nt][0], c1 = acc[mt][nt][1];
                float c2 = acc[mt][nt][2], c3 = acc[mt][nt][3];
                float m3 = c3;
                float m2 = (ss.z == ss.w) ? fmaxf(c2, m3) : c2;
                float m1 = (ss.y == ss.z) ? fmaxf(c1, m2) : c1;
                float m0 = (ss.x == ss.y) ? fmaxf(c0, m1) : c0;
                if (ss.x >= 0)                 atomicMax(&accs[(int)ss.x * ACCSTR + colw], encf(m0));
                if (ss.y >= 0 && ss.y != ss.x) atomicMax(&accs[(int)ss.y * ACCSTR + colw], encf(m1));
                if (ss.z >= 0 && ss.z != ss.y) atomicMax(&accs[(int)ss.z * ACCSTR + colw], encf(m2));
                if (ss.w >= 0 && ss.w != ss.z) atomicMax(&accs[(int)ss.w * ACCSTR + colw], encf(m3));
            }
        }
    };

    char4 ssp0 = make_char4(-1, -1, -1, -1), ssp1 = make_char4(-1, -1, -1, -1);
    int prevbuf = 0;

    for (int t = 0; t < ntile; t++) {
        int cur = t & 1;

        // (1) capture tile-t metadata; issue gathered-V loads EARLY
        int msrc[NPASS]; int msl[NPASS];
#pragma unroll
        for (int ps = 0; ps < NPASS; ps++) {
            int r = ps * RPP + rid;
            msrc[ps] = srcA[cur][r];
            msl[ps] = slotB[cur][r];
        }
        uint4 vreg[NPASS];
#pragma unroll
        for (int ps = 0; ps < NPASS; ps++)
            vreg[ps] = *(const uint4*)&Vb[(size_t)msrc[ps] * H + kk];   // src=0 for pad rows: safe
        char4 ssc0 = *(const char4*)&slotB[cur][rw * 32 + qd * 4];
        char4 ssc1 = *(const char4*)&slotB[cur][rw * 32 + 16 + qd * 4];

        // (2) prefetch CSR metadata for tile t+1 into registers
        int nsrc = 0; signed char nsl = -1;
        bool hn = (t + 1 < ntile);
        if (hn && tid < TR) {
            int p = e0 + (t + 1) * TR + tid;
            if (p < e1) { nsrc = csr_src[p]; nsl = (signed char)(csr_dst[p] - n0); }
        }

        // (3) MFMA + seg-max for tile t-1 — hides the V-gather latency
        if (t > 0) mfma_tile(prevbuf, ssp0, ssp1);

        // (4) build hidden tile t: hs = bf16(relu(U[dst] + V[src]))
#pragma unroll
        for (int ps = 0; ps < NPASS; ps++) {
            int r = ps * RPP + rid;
            uint4 w;
            if (msl[ps] >= 0) {
                const float4 ua = *(const float4*)&U[(size_t)(n0 + msl[ps]) * H + kk];
                const float4 ub = *(const float4*)&U[(size_t)(n0 + msl[ps]) * H + kk + 4];
                const uint4 vv = vreg[ps];
                w.x = pk2(fmaxf(ua.x + bflo(vv.x), 0.f), fmaxf(ua.y + bfhi(vv.x), 0.f));
                w.y = pk2(fmaxf(ua.z + bflo(vv.y), 0.f), fmaxf(ua.w + bfhi(vv.y), 0.f));
                w.z = pk2(fmaxf(ub.x + bflo(vv.z), 0.f), fmaxf(ub.y + bfhi(vv.z), 0.f));
                w.w = pk2(fmaxf(ub.z + bflo(vv.w), 0.f), fmaxf(ub.w + bfhi(vv.w), 0.f));
            } else {
                w = (uint4){0u, 0u, 0u, 0u};
            }
            *(uint4*)&hs[cur][r * HP + kk] = w;
        }

        // (5) stage next tile's CSR metadata into the other buffer
        if (hn && tid < TR) { srcA[cur ^ 1][tid] = nsrc; slotB[cur ^ 1][tid] = nsl; }

        // (6) single barrier per tile
        __syncthreads();
        ssp0 = ssc0; ssp1 = ssc1; prevbuf = cur;
    }
    if (ntile > 0) mfma_tile(prevbuf, ssp0, ssp1);
    __syncthreads();

    for (int idx = tid; idx < 16 * F; idx += BLOCK) {
        int sl = idx / F, cc = idx % F;
        float m = decf(accs[sl * ACCSTR + cc]);
        float o = isfinite(m) ? (m + B2[cc]) : 0.f;   // empty segment -> 0
        Y[(size_t)(n0 + sl) * F + cc] = o;
    }
}

// ============================ global max-pool + FC ============================
__global__ void k_pool(const float* __restrict__ X3, const int* __restrict__ batch,
                       unsigned* poolEnc) {
    int gph = blockIdx.x;
    int seg = blockIdx.y;
    int c = threadIdx.x;
    int lo = 0, hi = NNODES;
    while (lo < hi) { int mid = (lo + hi) >> 1; if (batch[mid] < gph) lo = mid + 1; else hi = mid; }
    int start = lo;
    hi = NNODES;
    while (lo < hi) { int mid = (lo + hi) >> 1; if (batch[mid] < gph + 1) lo = mid + 1; else hi = mid; }
    int end = lo;
    int chunk = (end - start + 7) >> 3;
    int s = start + seg * chunk;
    int e = min(end, s + chunk);
    float m = -INFINITY;
    for (int n = s; n < e; n++) m = fmaxf(m, X3[(size_t)n * 256 + c]);
    atomicMax(&poolEnc[gph * 256 + c], encf(m));
}

__global__ __launch_bounds__(128) void k_fc(const unsigned* __restrict__ poolEnc,
                                            const float* __restrict__ Wfc,
                                            const float* __restrict__ Bfc,
                                            float* __restrict__ out) {
    __shared__ float p[256];
    int gph = blockIdx.x, c = threadIdx.x;
    for (int k = c; k < 256; k += 128) {
        float m = decf(poolEnc[gph * 256 + k]);
        p[k] = isfinite(m) ? m : 0.f;
    }
    __syncthreads();
    float s = Bfc[c];
    for (int k = 0; k < 256; k++) s += p[k] * Wfc[k * 128 + c];
    out[gph * 128 + c] = s;
}

// ============================ launch ============================
extern "C" void kernel_launch(void* const* d_in, const int* in_sizes, int n_in,
                              void* d_out, int out_size, void* d_ws, size_t ws_size,
                              hipStream_t stream) {
    const float* x     = (const float*)d_in[0];
    const int*   ei    = (const int*)d_in[1];
    const int*   batch = (const int*)d_in[2];
    const float* w1_1 = (const float*)d_in[3];
    const float* b1_1 = (const float*)d_in[4];
    const float* w2_1 = (const float*)d_in[5];
    const float* b2_1 = (const float*)d_in[6];
    const float* w1_2 = (const float*)d_in[7];
    const float* b1_2 = (const float*)d_in[8];
    const float* w2_2 = (const float*)d_in[9];
    const float* b2_2 = (const float*)d_in[10];
    const float* w1_3 = (const float*)d_in[11];
    const float* b1_3 = (const float*)d_in[12];
    const float* w2_3 = (const float*)d_in[13];
    const float* b2_3 = (const float*)d_in[14];
    const float* wfc  = (const float*)d_in[15];
    const float* bfc  = (const float*)d_in[16];
    float* out = (float*)d_out;

    char* ws = (char*)d_ws;
    size_t off = 0;
    auto alloc = [&](size_t bytes) {
        void* p = ws + off;
        off = (off + bytes + 255) & ~(size_t)255;
        return p;
    };
    int* deg      = (int*)alloc((size_t)NNODES * 4);
    int* cursor   = (int*)alloc((size_t)NNODES * 4);
    int* rowptr   = (int*)alloc((size_t)(NNODES + 1) * 4);
    int* bsum     = (int*)alloc(256 * 4);
    int* boff     = (int*)alloc(256 * 4);
    int* csr_src  = (int*)alloc((size_t)NEDGES * 4);
    int* csr_dst  = (int*)alloc((size_t)NEDGES * 4);
    float* U      = (float*)alloc((size_t)NNODES * 256 * 4);
    unsigned short* V = (unsigned short*)alloc((size_t)NNODES * 256 * 2);
    float* x1     = (float*)alloc((size_t)NNODES * 64 * 4);
    float* x2     = (float*)alloc((size_t)NNODES * 128 * 4);
    float* x3     = (float*)alloc((size_t)NNODES * 256 * 4);
    unsigned* poolEnc = (unsigned*)alloc((size_t)NGRAPHS * 256 * 4);
    (void)ws_size; (void)in_sizes; (void)n_in; (void)out_size;

    // CSR by dst (shared across the 3 layers)
    k_init<<<256, 256, 0, stream>>>(deg, cursor, poolEnc);
    k_count<<<NEDGES / 256, 256, 0, stream>>>(ei, deg);
    k_scan1<<<256, 256, 0, stream>>>(deg, rowptr, bsum);
    k_scan2<<<1, 256, 0, stream>>>(bsum, boff);
    k_scan3<<<256, 256, 0, stream>>>(rowptr, boff);
    k_scatter<<<NEDGES / 256, 256, 0, stream>>>(ei, rowptr, cursor, csr_src, csr_dst);

    // layer 1: F_in=3, H=64, F=64   (2x2 waves, TR=64, Bf=16 regs, NPASS=2)
    k_uv<3, 64><<<NNODES / 16, 256, 0, stream>>>(x, w1_1, b1_1, U, V);
    k_agg<64, 64, 2, 2><<<NNODES / 16, 256, 0, stream>>>(U, V, w2_1, b2_1, rowptr, csr_src, csr_dst, x1);
    // layer 2: F_in=64, H=128, F=128  (1x8 waves, 512 thr, CPW=16, Bf=16 regs)
    k_uv<64, 128><<<NNODES / 16, 256, 0, stream>>>(x1, w1_2, b1_2, U, V);
    k_agg<128, 128, 1, 8><<<NNODES / 16, 512, 0, stream>>>(U, V, w2_2, b2_2, rowptr, csr_src, csr_dst, x2);
    // layer 3: F_in=128, H=256, F=256  (1x16 waves, 1024 thr, CPW=16, Bf=32 regs)
    k_uv<128, 256><<<NNODES / 16, 256, 0, stream>>>(x2, w1_3, b1_3, U, V);
    k_agg<256, 256, 1, 16><<<NNODES / 16, 1024, 0, stream>>>(U, V, w2_3, b2_3, rowptr, csr_src, csr_dst, x3);

    // global max pool + FC
    k_pool<<<dim3(NGRAPHS, 8), 256, 0, stream>>>(x3, batch, poolEnc);
    k_fc<<<NGRAPHS, 128, 0, stream>>>(poolEnc, wfc, bfc, out);
}